// Round 1
// baseline (706.305 us; speedup 1.0000x reference)
//
#include <hip/hip_runtime.h>
#include <math.h>

// Problem dims
constexpr int kH  = 1024;
constexpr int kV  = 50257;
constexpr int kS  = 4096;
constexpr int kH4 = kH / 4;    // 256 float4 per H row
constexpr int kH2 = 2 * kH;    // 2048

// Workspace layout (float offsets) — all 16B-aligned
constexpr int WS_H0     = 0;       // 1024
constexpr int WS_GH1    = 1024;    // 3072
constexpr int WS_H1     = 4096;    // 1024
constexpr int WS_V      = 5120;    // 1024
constexpr int WS_CTX    = 6144;    // 1024
constexpr int WS_ATTN   = 7168;    // 4096
constexpr int WS_E      = 11264;   // 4096
constexpr int WS_SC     = 15360;   // [0]=c  [1]=max  [2]=lse
constexpr int WS_PM     = 15424;   // 64
constexpr int WS_PS     = 15488;   // 64
constexpr int WS_LOGITS = 15552;   // 50257
// total 65809 floats ~ 258 KB

// d_out layout (floats): logits | context | hidden(h0,h1) | attn
constexpr int OUT_LOGITS = 0;
constexpr int OUT_CTX    = kV;                 // 50257 (NOT 16B aligned -> scalar stores only)
constexpr int OUT_HID    = kV + kH;            // 51281
constexpr int OUT_ATTN   = kV + kH + 2 * kH;   // 53329

__device__ __forceinline__ float wred_sum(float v) {
#pragma unroll
  for (int o = 32; o > 0; o >>= 1) v += __shfl_down(v, o, 64);
  return v;  // valid in lane 0
}
__device__ __forceinline__ float wred_max(float v) {
#pragma unroll
  for (int o = 32; o > 0; o >>= 1) v = fmaxf(v, __shfl_down(v, o, 64));
  return v;  // valid in lane 0
}
__device__ __forceinline__ float sigmoidf_(float x) { return 1.0f / (1.0f + __expf(-x)); }
__device__ __forceinline__ float dot4(float4 a, float4 b) {
  return a.x * b.x + a.y * b.y + a.z * b.z + a.w * b.w;
}

// K1: blocks [0,256): GRU0 -> h0 ; blocks [256,1024): gh1 = W_hh1 @ h_prev1 + b_hh1
__global__ void k1_gru0_gh1(const int* __restrict__ wi_p, const float* __restrict__ lc,
                            const float* __restrict__ lh, const float* __restrict__ emb,
                            const float* __restrict__ W_ih0, const float* __restrict__ W_hh0,
                            const float* __restrict__ b_ih0, const float* __restrict__ b_hh0,
                            const float* __restrict__ W_hh1, const float* __restrict__ b_hh1,
                            float* __restrict__ ws) {
  const int wave = threadIdx.x >> 6, lane = threadIdx.x & 63;
  const int b = blockIdx.x;
  if (b < 256) {
    const int j = b * 4 + wave;
    const int wi = wi_p[0];
    const float4* embr = (const float4*)(emb + (size_t)wi * kH);
    const float4* lc4  = (const float4*)lc;
    const float4* Wr = (const float4*)(W_ih0 + (size_t)j * kH2);
    const float4* Wz = (const float4*)(W_ih0 + (size_t)(j + kH) * kH2);
    const float4* Wn = (const float4*)(W_ih0 + (size_t)(j + 2 * kH) * kH2);
    float ar = 0.f, az = 0.f, an = 0.f;
#pragma unroll
    for (int i = 0; i < 8; i++) {
      const int idx = lane + i * 64;  // over 512 float4 = 2048 floats
      const float4 xv = (idx < kH4) ? embr[idx] : lc4[idx - kH4];
      ar += dot4(Wr[idx], xv);
      az += dot4(Wz[idx], xv);
      an += dot4(Wn[idx], xv);
    }
    const float4* Ur = (const float4*)(W_hh0 + (size_t)j * kH);
    const float4* Uz = (const float4*)(W_hh0 + (size_t)(j + kH) * kH);
    const float4* Un = (const float4*)(W_hh0 + (size_t)(j + 2 * kH) * kH);
    const float4* h4 = (const float4*)lh;  // h_prev0 = last_hidden[0]
    float br = 0.f, bz = 0.f, bn = 0.f;
#pragma unroll
    for (int i = 0; i < 4; i++) {
      const int idx = lane + i * 64;  // over 256 float4 = 1024 floats
      const float4 hv = h4[idx];
      br += dot4(Ur[idx], hv);
      bz += dot4(Uz[idx], hv);
      bn += dot4(Un[idx], hv);
    }
    ar = wred_sum(ar); az = wred_sum(az); an = wred_sum(an);
    br = wred_sum(br); bz = wred_sum(bz); bn = wred_sum(bn);
    if (lane == 0) {
      const float ir = ar + b_ih0[j],          hr = br + b_hh0[j];
      const float iz = az + b_ih0[j + kH],     hz = bz + b_hh0[j + kH];
      const float in_ = an + b_ih0[j + 2 * kH], hn = bn + b_hh0[j + 2 * kH];
      const float r = sigmoidf_(ir + hr);
      const float z = sigmoidf_(iz + hz);
      const float n = tanhf(in_ + r * hn);
      ws[WS_H0 + j] = (1.f - z) * n + z * lh[j];
    }
  } else {
    const int row = (b - 256) * 4 + wave;  // [0, 3072)
    const float4* W  = (const float4*)(W_hh1 + (size_t)row * kH);
    const float4* h4 = (const float4*)(lh + kH);  // h_prev1
    float a = 0.f;
#pragma unroll
    for (int i = 0; i < 4; i++) {
      const int idx = lane + i * 64;
      a += dot4(W[idx], h4[idx]);
    }
    a = wred_sum(a);
    if (lane == 0) ws[WS_GH1 + row] = a + b_hh1[row];
  }
}

// K2: GRU1 -> h1 ; write hidden outputs ; zero v accumulator
__global__ void k2_gru1(const float* __restrict__ lh, const float* __restrict__ W_ih1,
                        const float* __restrict__ b_ih1, float* __restrict__ ws,
                        float* __restrict__ out) {
  const int wave = threadIdx.x >> 6, lane = threadIdx.x & 63;
  const int j = blockIdx.x * 4 + wave;
  const float4* x4 = (const float4*)(ws + WS_H0);
  const float4* Wr = (const float4*)(W_ih1 + (size_t)j * kH);
  const float4* Wz = (const float4*)(W_ih1 + (size_t)(j + kH) * kH);
  const float4* Wn = (const float4*)(W_ih1 + (size_t)(j + 2 * kH) * kH);
  float ar = 0.f, az = 0.f, an = 0.f;
#pragma unroll
  for (int i = 0; i < 4; i++) {
    const int idx = lane + i * 64;
    const float4 xv = x4[idx];
    ar += dot4(Wr[idx], xv);
    az += dot4(Wz[idx], xv);
    an += dot4(Wn[idx], xv);
  }
  ar = wred_sum(ar); az = wred_sum(az); an = wred_sum(an);
  if (lane == 0) {
    const float r = sigmoidf_(ar + b_ih1[j] + ws[WS_GH1 + j]);
    const float z = sigmoidf_(az + b_ih1[j + kH] + ws[WS_GH1 + j + kH]);
    const float n = tanhf(an + b_ih1[j + 2 * kH] + r * ws[WS_GH1 + j + 2 * kH]);
    const float h1 = (1.f - z) * n + z * lh[kH + j];
    ws[WS_H1 + j] = h1;
    out[OUT_HID + kH + j] = h1;          // hidden[1]
    out[OUT_HID + j] = ws[WS_H0 + j];    // hidden[0]
  }
  if (blockIdx.x < 4) ws[WS_V + blockIdx.x * 256 + threadIdx.x] = 0.f;  // zero v
}

// K3: v = W_attn.T @ h1 (atomic partials) ; c = dot(b_attn, h1)
__global__ void k3_attnv(const float* __restrict__ W_attn, const float* __restrict__ b_attn,
                         float* __restrict__ ws) {
  __shared__ float red[4];
  const int b = blockIdx.x, t = threadIdx.x;
  const int wave = t >> 6, lane = t & 63;
  if (b < 64) {
    const float4* W4 = (const float4*)W_attn;
    float4 acc = make_float4(0.f, 0.f, 0.f, 0.f);
    const int j0 = b * 16;
#pragma unroll
    for (int jj = 0; jj < 16; jj++) {
      const int j = j0 + jj;
      const float s = ws[WS_H1 + j];
      const float4 w = W4[(size_t)j * kH4 + t];
      acc.x += s * w.x; acc.y += s * w.y; acc.z += s * w.z; acc.w += s * w.w;
    }
    atomicAdd(&ws[WS_V + 4 * t + 0], acc.x);
    atomicAdd(&ws[WS_V + 4 * t + 1], acc.y);
    atomicAdd(&ws[WS_V + 4 * t + 2], acc.z);
    atomicAdd(&ws[WS_V + 4 * t + 3], acc.w);
  } else {
    float a = 0.f;
    for (int i = t; i < kH; i += 256) a += b_attn[i] * ws[WS_H1 + i];
    const float wsum = wred_sum(a);
    if (lane == 0) red[wave] = wsum;
    __syncthreads();
    if (t == 0) ws[WS_SC + 0] = red[0] + red[1] + red[2] + red[3];
  }
}

// K4: energies[s] = dot(enc[s], v) + c
__global__ void k4_energies(const float* __restrict__ enc, float* __restrict__ ws) {
  const int wave = threadIdx.x >> 6, lane = threadIdx.x & 63;
  const int s = blockIdx.x * 4 + wave;
  const float4* e4 = (const float4*)(enc + (size_t)s * kH);
  const float4* v4 = (const float4*)(ws + WS_V);
  float a = 0.f;
#pragma unroll
  for (int i = 0; i < 4; i++) {
    const int idx = lane + i * 64;
    a += dot4(e4[idx], v4[idx]);
  }
  a = wred_sum(a);
  if (lane == 0) ws[WS_E + s] = a + ws[WS_SC + 0];
}

// K5: softmax over S=4096 (one block, 1024 threads); write attn out; zero ctx accumulator
__global__ void k5_softmax(float* __restrict__ ws, float* __restrict__ out) {
  __shared__ float red[16];
  const int t = threadIdx.x, lane = t & 63, wave = t >> 6;
  const float4 e = ((const float4*)(ws + WS_E))[t];
  float m = fmaxf(fmaxf(e.x, e.y), fmaxf(e.z, e.w));
  float wm = wred_max(m);
  if (lane == 0) red[wave] = wm;
  __syncthreads();
  if (wave == 0) {
    float x = (lane < 16) ? red[lane] : -INFINITY;
    x = wred_max(x);
    if (lane == 0) red[0] = x;
  }
  __syncthreads();
  m = red[0];
  __syncthreads();
  float4 ex;
  ex.x = __expf(e.x - m); ex.y = __expf(e.y - m);
  ex.z = __expf(e.z - m); ex.w = __expf(e.w - m);
  float s = ex.x + ex.y + ex.z + ex.w;
  float wsum = wred_sum(s);
  if (lane == 0) red[wave] = wsum;
  __syncthreads();
  if (wave == 0) {
    float x = (lane < 16) ? red[lane] : 0.f;
    x = wred_sum(x);
    if (lane == 0) red[0] = x;
  }
  __syncthreads();
  const float inv = 1.0f / red[0];
  float4 a4 = make_float4(ex.x * inv, ex.y * inv, ex.z * inv, ex.w * inv);
  ((float4*)(ws + WS_ATTN))[t] = a4;
  // d_out attn region is only 4B-aligned -> scalar stores
  out[OUT_ATTN + 4 * t + 0] = a4.x;
  out[OUT_ATTN + 4 * t + 1] = a4.y;
  out[OUT_ATTN + 4 * t + 2] = a4.z;
  out[OUT_ATTN + 4 * t + 3] = a4.w;
  ws[WS_CTX + t] = 0.f;  // zero context accumulator (t < 1024)
}

// K6: context = attn @ enc  (64 blocks x 64 rows each, atomic partials)
__global__ void k6_context(const float* __restrict__ enc, float* __restrict__ ws) {
  const int b = blockIdx.x, t = threadIdx.x;
  const float4* e4 = (const float4*)enc;
  float4 acc = make_float4(0.f, 0.f, 0.f, 0.f);
  const int s0 = b * 64;
  for (int ss = 0; ss < 64; ss++) {
    const int s = s0 + ss;
    const float a = ws[WS_ATTN + s];
    const float4 ev = e4[(size_t)s * kH4 + t];
    acc.x += a * ev.x; acc.y += a * ev.y; acc.z += a * ev.z; acc.w += a * ev.w;
  }
  atomicAdd(&ws[WS_CTX + 4 * t + 0], acc.x);
  atomicAdd(&ws[WS_CTX + 4 * t + 1], acc.y);
  atomicAdd(&ws[WS_CTX + 4 * t + 2], acc.z);
  atomicAdd(&ws[WS_CTX + 4 * t + 3], acc.w);
}

// K7: logits = W_out @ [h1 ; ctx] + b_out   (the 412 MB streaming kernel)
__global__ void k7_logits(const float* __restrict__ W_out, const float* __restrict__ b_out,
                          float* __restrict__ ws) {
  const int wave = threadIdx.x >> 6, lane = threadIdx.x & 63;
  const int row = blockIdx.x * 4 + wave;
  if (row >= kV) return;
  const float4* W4 = (const float4*)(W_out + (size_t)row * kH2);
  const float4* h14 = (const float4*)(ws + WS_H1);
  const float4* c4  = (const float4*)(ws + WS_CTX);
  float a = 0.f;
#pragma unroll
  for (int i = 0; i < 8; i++) {
    const int idx = lane + i * 64;  // over 512 float4
    const float4 xv = (idx < kH4) ? h14[idx] : c4[idx - kH4];
    a += dot4(W4[idx], xv);
  }
  a = wred_sum(a);
  if (lane == 0) ws[WS_LOGITS + row] = a + b_out[row];
}

// K8a: per-block (max, sumexp) partials over logits
__global__ void k8a_partial(float* __restrict__ ws) {
  __shared__ float red[4];
  const int b = blockIdx.x, t = threadIdx.x;
  const int wave = t >> 6, lane = t & 63;
  const int g0 = b * 256 + t;
  float vals[4];
  int nv = 0;
  float m = -INFINITY;
  for (int g = g0; g < kV; g += 64 * 256) {
    const float x = ws[WS_LOGITS + g];
    vals[nv++] = x;
    m = fmaxf(m, x);
  }
  float wm = wred_max(m);
  if (lane == 0) red[wave] = wm;
  __syncthreads();
  const float bm = fmaxf(fmaxf(red[0], red[1]), fmaxf(red[2], red[3]));
  float s = 0.f;
  for (int i = 0; i < nv; i++) s += __expf(vals[i] - bm);
  float wsum = wred_sum(s);
  __syncthreads();
  if (lane == 0) red[wave] = wsum;
  __syncthreads();
  if (t == 0) {
    ws[WS_PM + b] = bm;
    ws[WS_PS + b] = red[0] + red[1] + red[2] + red[3];
  }
}

// K8b: combine 64 partials -> global max, log-sum-exp (one wave)
__global__ void k8b_combine(float* __restrict__ ws) {
  const int lane = threadIdx.x;
  const float m = ws[WS_PM + lane];
  float gm = wred_max(m);
  gm = __shfl(gm, 0, 64);
  const float s = ws[WS_PS + lane] * __expf(m - gm);
  const float gs = wred_sum(s);
  if (lane == 0) {
    ws[WS_SC + 1] = gm;
    ws[WS_SC + 2] = logf(gs);
  }
}

// K8c: final writes — log-softmax output + context copy
__global__ void k8c_output(const float* __restrict__ ws, float* __restrict__ out) {
  const int g = blockIdx.x * 256 + threadIdx.x;
  const float shift = ws[WS_SC + 1] + ws[WS_SC + 2];
  if (g < kV) out[OUT_LOGITS + g] = ws[WS_LOGITS + g] - shift;
  if (g < kH) out[OUT_CTX + g] = ws[WS_CTX + g];
}

extern "C" void kernel_launch(void* const* d_in, const int* in_sizes, int n_in,
                              void* d_out, int out_size, void* d_ws, size_t ws_size,
                              hipStream_t stream) {
  const int*   wi     = (const int*)d_in[0];
  const float* lc     = (const float*)d_in[1];
  const float* lh     = (const float*)d_in[2];
  const float* enc    = (const float*)d_in[3];
  const float* emb    = (const float*)d_in[4];
  const float* W_ih0  = (const float*)d_in[5];
  const float* W_hh0  = (const float*)d_in[6];
  const float* b_ih0  = (const float*)d_in[7];
  const float* b_hh0  = (const float*)d_in[8];
  const float* W_ih1  = (const float*)d_in[9];
  const float* W_hh1  = (const float*)d_in[10];
  const float* b_ih1  = (const float*)d_in[11];
  const float* b_hh1  = (const float*)d_in[12];
  const float* W_attn = (const float*)d_in[13];
  const float* b_attn = (const float*)d_in[14];
  const float* W_out  = (const float*)d_in[15];
  const float* b_out  = (const float*)d_in[16];
  float* out = (float*)d_out;
  float* ws  = (float*)d_ws;

  k1_gru0_gh1<<<1024, 256, 0, stream>>>(wi, lc, lh, emb, W_ih0, W_hh0, b_ih0, b_hh0,
                                        W_hh1, b_hh1, ws);
  k2_gru1<<<256, 256, 0, stream>>>(lh, W_ih1, b_ih1, ws, out);
  k3_attnv<<<65, 256, 0, stream>>>(W_attn, b_attn, ws);
  k4_energies<<<1024, 256, 0, stream>>>(enc, ws);
  k5_softmax<<<1, 1024, 0, stream>>>(ws, out);
  k6_context<<<64, 256, 0, stream>>>(enc, ws);
  k7_logits<<<(kV + 3) / 4, 256, 0, stream>>>(W_out, b_out, ws);
  k8a_partial<<<64, 256, 0, stream>>>(ws);
  k8b_combine<<<1, 64, 0, stream>>>(ws);
  k8c_output<<<(kV + 255) / 256, 256, 0, stream>>>(ws, out);
}